// Round 6
// baseline (91.373 us; speedup 1.0000x reference)
//
#include <hip/hip_runtime.h>

// S6 selective scan: BT=8, L=8192, F=128, N=16
// y[b,t,f] = sum_n h[b,t,f,n]*C[b,t,n],  h = dA*h + dB*x  (diagonal A)
//
// Decomposition per chunk (LC=64):
//   y(t) = y_local(t) + sum_n E(t,n)*Hin(f,n),  E(t,n)=C(t,n)*exp(A_n*cumdelta(t))
//
// A: one wave per chunk. lane=token: projection (W via uniform/scalar loads,
//    x f4 from global), delta prefix-sum in-wave, G -> LDS only, E/S -> global.
//    Then lane=f-pair: local scan writes y_local (d_out) and q. No barriers.
// B: chunk-level scan q,(S,A) -> Hin (16-deep reg prefetch)
// C: y += E @ Hin  (streaming rank-16 correction)

#define BTc   8
#define Lseq  8192
#define Fdim  128
#define Ndim  16
#define CH    128          // number of chunks
#define LC    64           // Lseq / CH

__global__ __launch_bounds__(64) void k_fused(
    const float* __restrict__ x,
    const float* __restrict__ Wb, const float* __restrict__ bb,
    const float* __restrict__ Wc, const float* __restrict__ bc,
    const float* __restrict__ Wd, const float* __restrict__ bd,
    const float* __restrict__ A,
    float* __restrict__ ylocal,          // = d_out
    float* __restrict__ q, float* __restrict__ E, float* __restrict__ S)
{
    __shared__ float Gl[LC][52];         // dA|dB|C per token, 13.3 KB (52: f4-aligned rows)
    const int lane = threadIdx.x;        // 0..63
    const int c = blockIdx.x, b = blockIdx.y;
    const size_t tok0 = (size_t)b * Lseq + (size_t)c * LC;

    // ---- projection: lane = token; W indices wave-uniform -> scalar loads ----
    const float4* xt = reinterpret_cast<const float4*>(x + (tok0 + lane) * Fdim);
    float acc[33];
#pragma unroll
    for (int j = 0; j < 33; ++j) acc[j] = 0.f;

#pragma unroll 4
    for (int kk = 0; kk < 32; ++kk) {
        float4 xv = xt[kk];
        const float* wb0 = Wb + kk * 64;     // rows 4kk..4kk+3 of [128][16]
        const float* wc0 = Wc + kk * 64;
        const float* wd0 = Wd + kk * 4;
#pragma unroll
        for (int j = 0; j < 16; ++j) {
            acc[j]      = fmaf(xv.x, wb0[j],      acc[j]);
            acc[j]      = fmaf(xv.y, wb0[16 + j], acc[j]);
            acc[j]      = fmaf(xv.z, wb0[32 + j], acc[j]);
            acc[j]      = fmaf(xv.w, wb0[48 + j], acc[j]);
            acc[16 + j] = fmaf(xv.x, wc0[j],      acc[16 + j]);
            acc[16 + j] = fmaf(xv.y, wc0[16 + j], acc[16 + j]);
            acc[16 + j] = fmaf(xv.z, wc0[32 + j], acc[16 + j]);
            acc[16 + j] = fmaf(xv.w, wc0[48 + j], acc[16 + j]);
        }
        acc[32] = fmaf(xv.x, wd0[0], acc[32]);
        acc[32] = fmaf(xv.y, wd0[1], acc[32]);
        acc[32] = fmaf(xv.z, wd0[2], acc[32]);
        acc[32] = fmaf(xv.w, wd0[3], acc[32]);
    }

    // ---- post: delta, in-wave inclusive prefix sum, dA/dB/C/E ----
    float v = acc[32] + bd[0];
    float delta = fmaxf(v, 0.f) + log1pf(expf(-fabsf(v)));
    float cum = delta;
#pragma unroll
    for (int off = 1; off < 64; off <<= 1) {
        float up = __shfl_up(cum, off);
        cum += (lane >= off) ? up : 0.f;
    }
    if (lane == LC - 1) S[b * CH + c] = cum;

    {
        float dAv[16], dBv[16], Cv[16], Ev[16];
#pragma unroll
        for (int n = 0; n < 16; ++n) {
            float An = A[n];
            float dA = expf(delta * An);
            dAv[n] = dA;
            dBv[n] = (dA - 1.f) / An * (acc[n] + bb[n]);
            Cv[n]  = acc[16 + n] + bc[n];
            Ev[n]  = Cv[n] * expf(An * cum);
        }
        float4* gr = reinterpret_cast<float4*>(&Gl[lane][0]);
#pragma unroll
        for (int p = 0; p < 4; ++p) {
            gr[p]     = make_float4(dAv[4*p], dAv[4*p+1], dAv[4*p+2], dAv[4*p+3]);
            gr[4 + p] = make_float4(dBv[4*p], dBv[4*p+1], dBv[4*p+2], dBv[4*p+3]);
            gr[8 + p] = make_float4(Cv[4*p],  Cv[4*p+1],  Cv[4*p+2],  Cv[4*p+3]);
        }
        float4* Ep = reinterpret_cast<float4*>(E + ((size_t)(b * CH + c) * LC + lane) * 16);
#pragma unroll
        for (int p = 0; p < 4; ++p)
            Ep[p] = make_float4(Ev[4*p], Ev[4*p+1], Ev[4*p+2], Ev[4*p+3]);
    }
    // single wave: LDS write->read ordering handled by waitcnt, no barrier needed

    // ---- local scan: lane = f pair (f, f+64) ----
    float h0[16], h1[16];
#pragma unroll
    for (int n = 0; n < 16; ++n) { h0[n] = 0.f; h1[n] = 0.f; }

    const float* xs = x + tok0 * Fdim;
    float* yp = ylocal + tok0 * Fdim;
#pragma unroll 2
    for (int t = 0; t < LC; ++t) {
        float xv0 = xs[t * Fdim + lane];
        float xv1 = xs[t * Fdim + lane + 64];
        const float4* gp = reinterpret_cast<const float4*>(&Gl[t][0]);
        float da[16], db[16], cc[16];
#pragma unroll
        for (int p = 0; p < 4; ++p) {
            float4 a4 = gp[p], b4 = gp[4 + p], c4 = gp[8 + p];
            da[4*p] = a4.x; da[4*p+1] = a4.y; da[4*p+2] = a4.z; da[4*p+3] = a4.w;
            db[4*p] = b4.x; db[4*p+1] = b4.y; db[4*p+2] = b4.z; db[4*p+3] = b4.w;
            cc[4*p] = c4.x; cc[4*p+1] = c4.y; cc[4*p+2] = c4.z; cc[4*p+3] = c4.w;
        }
        float y0 = 0.f, y1 = 0.f;
#pragma unroll
        for (int n = 0; n < 16; ++n) {
            h0[n] = fmaf(da[n], h0[n], db[n] * xv0);
            h1[n] = fmaf(da[n], h1[n], db[n] * xv1);
            y0 = fmaf(cc[n], h0[n], y0);
            y1 = fmaf(cc[n], h1[n], y1);
        }
        yp[t * Fdim + lane]      = y0;
        yp[t * Fdim + lane + 64] = y1;
    }

    float4* qp0 = reinterpret_cast<float4*>(q + ((size_t)(b * CH + c) * Fdim + lane) * 16);
    float4* qp1 = reinterpret_cast<float4*>(q + ((size_t)(b * CH + c) * Fdim + lane + 64) * 16);
#pragma unroll
    for (int p = 0; p < 4; ++p) {
        qp0[p] = make_float4(h0[4*p], h0[4*p+1], h0[4*p+2], h0[4*p+3]);
        qp1[p] = make_float4(h1[4*p], h1[4*p+1], h1[4*p+2], h1[4*p+3]);
    }
}

__global__ __launch_bounds__(256) void k_chunkscan(
    const float* __restrict__ q, const float* __restrict__ S,
    const float* __restrict__ A, float* __restrict__ Hin)
{
    int id = blockIdx.x * 256 + threadIdx.x;   // 16384 = 8*128*16
    int b  = id >> 11;
    int fn = id & 2047;
    int n  = id & 15;
    float An = A[n];
    float H = 0.f;
    size_t qb = (size_t)b * CH * 2048 + fn;
    const float* Sb = S + b * CH;
    for (int cg = 0; cg < CH; cg += 16) {
        float Sr[16], qr[16];
#pragma unroll
        for (int i = 0; i < 16; ++i) {
            Sr[i] = Sb[cg + i];
            qr[i] = q[qb + (size_t)(cg + i) * 2048];
        }
#pragma unroll
        for (int i = 0; i < 16; ++i) {
            Hin[qb + (size_t)(cg + i) * 2048] = H;
            H = fmaf(__expf(An * Sr[i]), H, qr[i]);
        }
    }
}

__global__ __launch_bounds__(128) void k_correct(
    const float* __restrict__ Hin, const float* __restrict__ E,
    float* __restrict__ y)
{
    __shared__ float El[LC][16];
    const int c = blockIdx.x, b = blockIdx.y;
    const int f = threadIdx.x;

    const float4* Eg = reinterpret_cast<const float4*>(E + (size_t)(b * CH + c) * LC * 16);
    float4* Es = reinterpret_cast<float4*>(&El[0][0]);
    for (int i = f; i < LC * 4; i += 128) Es[i] = Eg[i];

    float hv[16];
    const float4* hp = reinterpret_cast<const float4*>(Hin + ((size_t)(b * CH + c) * Fdim + f) * 16);
#pragma unroll
    for (int p = 0; p < 4; ++p) {
        float4 t4 = hp[p];
        hv[4*p] = t4.x; hv[4*p+1] = t4.y; hv[4*p+2] = t4.z; hv[4*p+3] = t4.w;
    }
    __syncthreads();

    float* yp = y + ((size_t)b * Lseq + (size_t)c * LC) * Fdim + f;
#pragma unroll 4
    for (int t = 0; t < LC; ++t) {
        const float4* ep = reinterpret_cast<const float4*>(&El[t][0]);
        float acc = 0.f;
#pragma unroll
        for (int p = 0; p < 4; ++p) {
            float4 e4 = ep[p];
            acc = fmaf(e4.x, hv[4*p],     acc);
            acc = fmaf(e4.y, hv[4*p + 1], acc);
            acc = fmaf(e4.z, hv[4*p + 2], acc);
            acc = fmaf(e4.w, hv[4*p + 3], acc);
        }
        yp[t * Fdim] += acc;
    }
}

extern "C" void kernel_launch(void* const* d_in, const int* in_sizes, int n_in,
                              void* d_out, int out_size, void* d_ws, size_t ws_size,
                              hipStream_t stream) {
    const float* x  = (const float*)d_in[0];
    const float* Wb = (const float*)d_in[1];
    const float* bb = (const float*)d_in[2];
    const float* Wc = (const float*)d_in[3];
    const float* bc = (const float*)d_in[4];
    const float* Wd = (const float*)d_in[5];
    const float* bd = (const float*)d_in[6];
    const float* A  = (const float*)d_in[7];
    float* y = (float*)d_out;

    float* q   = (float*)d_ws;                           // 8*128*2048 = 8.4 MB
    float* Hin = q   + (size_t)BTc * CH * Fdim * Ndim;   // 8*128*2048 = 8.4 MB
    float* E   = Hin + (size_t)BTc * CH * Fdim * Ndim;   // 8*128*64*16= 4.2 MB
    float* S   = E   + (size_t)BTc * CH * LC * Ndim;     // 1024 floats

    k_fused<<<dim3(CH, BTc), 64, 0, stream>>>(x, Wb, bb, Wc, bc, Wd, bd, A,
                                              y, q, E, S);
    k_chunkscan<<<dim3(BTc * Fdim * Ndim / 256), 256, 0, stream>>>(q, S, A, Hin);
    k_correct<<<dim3(CH, BTc), 128, 0, stream>>>(Hin, E, y);
}